// Round 3
// baseline (567.124 us; speedup 1.0000x reference)
//
#include <hip/hip_runtime.h>
#include <math.h>

#define B_ 4
#define C_ 64
#define M_ 8
#define H_ 224
#define W_ 224
#define N_ (H_*W_)        // 50176
#define CN_ (C_*N_)       // 3211264
#define MN_ (M_*N_)       // 401408
#define BCN_ (B_*CN_)
#define BMN_ (B_*MN_)
#define NPG_ 392          // 128-px groups per image (k_vkm)
#define NPG2_ 196         // 256-px groups per image (k_fc1m, k_out)

typedef __attribute__((ext_vector_type(8))) short short8;   // 8 bf16 (4 VGPR)
typedef __attribute__((ext_vector_type(4))) float f32x4;
typedef __attribute__((ext_vector_type(4))) unsigned int uint4v;

__device__ __forceinline__ float relu6f(float v){ return fminf(fmaxf(v,0.0f),6.0f); }
__device__ __forceinline__ float softplusf(float v){
  return v > 0.0f ? v + log1pf(expf(-v)) : log1pf(expf(v));
}
__device__ __forceinline__ unsigned short f2bf(float f){   // RNE f32->bf16
  unsigned int u = __float_as_uint(f);
  u += 0x7FFFu + ((u >> 16) & 1u);
  return (unsigned short)(u >> 16);
}
// pack 8 floats -> short8 of bf16 (RNE via v_cvt_pk_bf16_f32)
__device__ __forceinline__ short8 pack8(float4 a, float4 b){
  unsigned int p0,p1,p2,p3;
  asm("v_cvt_pk_bf16_f32 %0, %1, %2" : "=v"(p0) : "v"(a.x), "v"(a.y));
  asm("v_cvt_pk_bf16_f32 %0, %1, %2" : "=v"(p1) : "v"(a.z), "v"(a.w));
  asm("v_cvt_pk_bf16_f32 %0, %1, %2" : "=v"(p2) : "v"(b.x), "v"(b.y));
  asm("v_cvt_pk_bf16_f32 %0, %1, %2" : "=v"(p3) : "v"(b.z), "v"(b.w));
  uint4v q = {p0,p1,p2,p3};
  return __builtin_bit_cast(short8, q);
}

// ---------------------------------------------------------------------------
// P0: x (fp32 NCHW) -> x_t (bf16, swizzled NHWC): elem = (b*N+px)*64 + (c ^ ((px&7)<<3))
// Pre-swizzled GLOBAL layout so consumers copy linearly to LDS and read
// B-fragments conflict-free (cg ^= px&7).
// ---------------------------------------------------------------------------
__global__ __launch_bounds__(256) void k_cast(const float* __restrict__ x,
                                              unsigned short* __restrict__ xt)
{
  __shared__ float t[64*65];
  const int tid = threadIdx.x;
  const int b  = blockIdx.x / 784;
  const int pg = blockIdx.x % 784;
  const int px0 = pg*64;
  const float* xb = x + (size_t)b*CN_ + px0;
  #pragma unroll
  for (int r = 0; r < 4; ++r) {
    const int c  = (tid>>4) + 16*r;
    const int p4 = (tid&15)<<2;
    const float4 v = *(const float4*)(xb + (size_t)c*N_ + p4);
    float* d = &t[c*65 + p4];
    d[0]=v.x; d[1]=v.y; d[2]=v.z; d[3]=v.w;
  }
  __syncthreads();
  const int px = tid & 63;
  const int swz = px & 7;                       // px0 is a multiple of 64
  unsigned short* ob = xt + ((size_t)b*N_ + px0 + px)*64;
  #pragma unroll
  for (int gg = 0; gg < 2; ++gg) {
    const int cg = ((tid>>6)<<1) + gg;
    const int c0 = cg<<3;
    unsigned int rr0,rr1,rr2,rr3;
    {
      const float* tc = &t[px];
      const float a0 = tc[(c0+0)*65], a1 = tc[(c0+1)*65];
      const float a2 = tc[(c0+2)*65], a3 = tc[(c0+3)*65];
      const float a4 = tc[(c0+4)*65], a5 = tc[(c0+5)*65];
      const float a6 = tc[(c0+6)*65], a7 = tc[(c0+7)*65];
      asm("v_cvt_pk_bf16_f32 %0, %1, %2" : "=v"(rr0) : "v"(a0), "v"(a1));
      asm("v_cvt_pk_bf16_f32 %0, %1, %2" : "=v"(rr1) : "v"(a2), "v"(a3));
      asm("v_cvt_pk_bf16_f32 %0, %1, %2" : "=v"(rr2) : "v"(a4), "v"(a5));
      asm("v_cvt_pk_bf16_f32 %0, %1, %2" : "=v"(rr3) : "v"(a6), "v"(a7));
    }
    uint4v q = {rr0,rr1,rr2,rr3};
    *(uint4v*)(ob + ((cg ^ swz)<<3)) = q;
  }
}

// ---------------------------------------------------------------------------
// K1 (MFMA): h = relu6(bn(conv1x1(x))), K = softplus(conv1x1(x)+kb), ks_part.
// W matrix extended to 80 rows: [0..63]=fc1_w, [64..71]=k_w, [72..79]=0.
// 256 px/block (4 waves x 64 px). A-frags VGPR-resident; B from swizzled LDS.
// D layout (m89): col=lane&15 (px), row=(lane>>4)*4+reg (oc within 16-tile).
// ---------------------------------------------------------------------------
__global__ __launch_bounds__(256) void k_fc1m(const unsigned short* __restrict__ xt,
                                              const float* __restrict__ w,
                                              const float* __restrict__ bn,
                                              const float* __restrict__ kw,
                                              const float* __restrict__ kb,
                                              float* __restrict__ h,
                                              float* __restrict__ Kq,
                                              float* __restrict__ ks_part)
{
  __shared__ unsigned short xl[256*64];     // 32 KB, swizzled (global is pre-swizzled)
  __shared__ float invb[2][64];
  __shared__ float ksl[4][8];
  const int tid = threadIdx.x;
  const int b   = blockIdx.x / NPG2_;
  const int pg  = blockIdx.x % NPG2_;
  const int pix0 = pg*256;

  { // linear 32 KB copy (pre-swizzled global -> LDS)
    const uint4v* src = (const uint4v*)(xt + ((size_t)b*N_ + pix0)*64);
    uint4v* dst = (uint4v*)xl;
    #pragma unroll
    for (int r = 0; r < 8; ++r) dst[r*256 + tid] = src[r*256 + tid];
  }
  if (tid < 64) {
    const float inv = bn[tid] / sqrtf(bn[192+tid] + 1e-5f);
    invb[0][tid] = inv;
    invb[1][tid] = bn[64+tid] - bn[128+tid]*inv;
  }
  const int lane = tid & 63, wv = tid >> 6;
  const int l15 = lane & 15, u = lane >> 4;

  // A-fragments (weights) in VGPRs: 5 oc-tiles x 2 k-steps
  short8 aw[5][2];
  #pragma unroll
  for (int t = 0; t < 5; ++t) {
    #pragma unroll
    for (int kk = 0; kk < 2; ++kk) {
      const int c0 = kk*32 + u*8;
      float4 f0 = {0,0,0,0}, f1 = {0,0,0,0};
      if (t < 4) {
        const float* wr = w + (t*16 + l15)*64 + c0;
        f0 = *(const float4*)wr; f1 = *(const float4*)(wr+4);
      } else if (l15 < 8) {
        const float* wr = kw + l15*64 + c0;
        f0 = *(const float4*)wr; f1 = *(const float4*)(wr+4);
      }
      aw[t][kk] = pack8(f0, f1);
    }
  }
  __syncthreads();

  f32x4 acc[5][4];
  #pragma unroll
  for (int t = 0; t < 5; ++t)
    #pragma unroll
    for (int s = 0; s < 4; ++s) acc[t][s] = (f32x4){0.f,0.f,0.f,0.f};

  const int pxw = wv*64;
  #pragma unroll
  for (int kk = 0; kk < 2; ++kk) {
    #pragma unroll
    for (int s = 0; s < 4; ++s) {
      const int pxl = pxw + s*16 + l15;
      const short8 bx = *(const short8*)(xl + pxl*64 + (((kk*4+u) ^ (pxl&7))<<3));
      #pragma unroll
      for (int t = 0; t < 5; ++t)
        acc[t][s] = __builtin_amdgcn_mfma_f32_16x16x32_bf16(aw[t][kk], bx, acc[t][s], 0, 0, 0);
    }
  }

  // h epilogue (tiles 0..3)
  float* hb = h + (size_t)b*CN_;
  #pragma unroll
  for (int t = 0; t < 4; ++t) {
    #pragma unroll
    for (int s = 0; s < 4; ++s) {
      const int px = pix0 + pxw + s*16 + l15;
      #pragma unroll
      for (int r = 0; r < 4; ++r) {
        const int oc = t*16 + u*4 + r;
        hb[(size_t)oc*N_ + px] = relu6f(fmaf(acc[t][s][r], invb[0][oc], invb[1][oc]));
      }
    }
  }
  // K epilogue (tile 4, rows 0..7 valid -> u<2)
  float ksr[4] = {0.f,0.f,0.f,0.f};
  if (u < 2) {
    #pragma unroll
    for (int s = 0; s < 4; ++s) {
      const int px = pix0 + pxw + s*16 + l15;
      #pragma unroll
      for (int r = 0; r < 4; ++r) {
        const int m = u*4 + r;
        const float kq = softplusf(acc[4][s][r] + kb[m]);
        Kq[(size_t)b*MN_ + (size_t)m*N_ + px] = kq;
        ksr[r] += kq;
      }
    }
  }
  #pragma unroll
  for (int r = 0; r < 4; ++r) {
    float v = ksr[r];
    v += __shfl_xor(v, 1); v += __shfl_xor(v, 2);
    v += __shfl_xor(v, 4); v += __shfl_xor(v, 8);
    ksr[r] = v;
  }
  if (l15 == 0 && u < 2) {
    #pragma unroll
    for (int r = 0; r < 4; ++r) ksl[wv][u*4+r] = ksr[r];
  }
  __syncthreads();
  if (tid < 8)
    ks_part[(size_t)blockIdx.x*8 + tid] = (ksl[0][tid]+ksl[1][tid]) + (ksl[2][tid]+ksl[3][tid]);
}

// ---------------------------------------------------------------------------
// K2: s = relu6(bn1(dw5x5(h))) + relu6(bn2(dw3x3(h))); writes s_t bf16
// swizzled-NHWC (same global layout as x_t) for k_vkm's MFMA consumption.
// ---------------------------------------------------------------------------
__global__ __launch_bounds__(256) void k_dw(const float* __restrict__ h,
                                            const float* __restrict__ w5,
                                            const float* __restrict__ w3,
                                            const float* __restrict__ bn1,
                                            const float* __restrict__ bn2,
                                            unsigned short* __restrict__ st)
{
  __shared__ float tile[36*37];
  const int tid = threadIdx.x;
  const int blk = blockIdx.x;              // B*C*49
  const int t   = blk % 49;
  const int bc  = blk / 49;
  const int c   = bc & 63;
  const int tx0 = (t % 7) * 32;
  const int ty0 = (t / 7) * 32;
  const float* hb = h + (size_t)bc * N_;

  for (int idx = tid; idx < 1296; idx += 256) {
    const int ly = idx / 36, lx = idx - ly*36;
    const int gy = ty0 + ly - 2, gx = tx0 + lx - 2;
    float v = 0.0f;
    if (gy >= 0 && gy < H_ && gx >= 0 && gx < W_) v = hb[gy*W_ + gx];
    tile[ly*37 + lx] = v;
  }
  __syncthreads();

  float w5r[25], w3r[9];
  #pragma unroll
  for (int i = 0; i < 25; ++i) w5r[i] = w5[c*25 + i];
  #pragma unroll
  for (int i = 0; i < 9; ++i)  w3r[i] = w3[c*9 + i];
  const float inv1 = bn1[c] / sqrtf(bn1[192+c] + 1e-5f);
  const float bet1 = bn1[64+c] - bn1[128+c]*inv1;
  const float inv2 = bn2[c] / sqrtf(bn2[192+c] + 1e-5f);
  const float bet2 = bn2[64+c] - bn2[128+c]*inv2;

  const int ty  = tid >> 3;
  const int tx4 = (tid & 7) << 2;
  float a5[4] = {0,0,0,0}, a3[4] = {0,0,0,0};
  #pragma unroll
  for (int dy = 0; dy < 5; ++dy) {
    float r[8];
    #pragma unroll
    for (int i = 0; i < 8; ++i) r[i] = tile[(ty+dy)*37 + tx4 + i];
    #pragma unroll
    for (int dx = 0; dx < 5; ++dx) {
      const float wv = w5r[dy*5+dx];
      #pragma unroll
      for (int p = 0; p < 4; ++p) a5[p] = fmaf(wv, r[p+dx], a5[p]);
    }
    if (dy >= 1 && dy <= 3) {
      #pragma unroll
      for (int dx = 1; dx <= 3; ++dx) {
        const float wv = w3r[(dy-1)*3+(dx-1)];
        #pragma unroll
        for (int p = 0; p < 4; ++p) a3[p] = fmaf(wv, r[p+dx], a3[p]);
      }
    }
  }
  const int b = bc >> 6;
  const int pxr = tx0 + tx4;
  const int pxg = (ty0+ty)*W_ + pxr;
  unsigned short* ob = st + ((size_t)b*N_ + pxg)*64;
  float o[4];
  o[0] = relu6f(fmaf(a5[0],inv1,bet1)) + relu6f(fmaf(a3[0],inv2,bet2));
  o[1] = relu6f(fmaf(a5[1],inv1,bet1)) + relu6f(fmaf(a3[1],inv2,bet2));
  o[2] = relu6f(fmaf(a5[2],inv1,bet1)) + relu6f(fmaf(a3[2],inv2,bet2));
  o[3] = relu6f(fmaf(a5[3],inv1,bet1)) + relu6f(fmaf(a3[3],inv2,bet2));
  #pragma unroll
  for (int p = 0; p < 4; ++p)
    ob[(size_t)p*64 + (c ^ (((pxr+p)&7)<<3))] = f2bf(o[p]);
}

// ---------------------------------------------------------------------------
// K3 (MFMA): V = conv1x1(x,v_w)+v_b + relu6(bn(conv1x1(s,fc2_w))) in D-frags;
// KV partial via 16-value halving butterfly over l&15 (px), per-block store.
// 128 px/block, wave owns 32 px (2 subtiles) x 64 oc (4 tiles).
// ---------------------------------------------------------------------------
__global__ __launch_bounds__(256) void k_vkm(const unsigned short* __restrict__ xt,
                                             const unsigned short* __restrict__ st,
                                             const float* __restrict__ vw,
                                             const float* __restrict__ vb,
                                             const float* __restrict__ fw,
                                             const float* __restrict__ fbn,
                                             const float* __restrict__ Kq,
                                             float* __restrict__ kv_part)
{
  __shared__ unsigned short xl[128*64];   // 16 KB
  __shared__ unsigned short sl[128*64];   // 16 KB
  __shared__ float kl[8*128];             // 4 KB
  __shared__ float invb[3][64];
  __shared__ float kvw[4][512];           // 8 KB
  const int tid = threadIdx.x;
  const int b   = blockIdx.x / NPG_;
  const int pg  = blockIdx.x % NPG_;
  const int pix0 = pg*128;

  { // linear copies
    const size_t gb = ((size_t)b*N_ + pix0)*64;
    const uint4v* sx = (const uint4v*)(xt + gb);
    const uint4v* ss = (const uint4v*)(st + gb);
    uint4v* dx = (uint4v*)xl;
    uint4v* ds = (uint4v*)sl;
    #pragma unroll
    for (int r = 0; r < 4; ++r) {
      dx[r*256 + tid] = sx[r*256 + tid];
      ds[r*256 + tid] = ss[r*256 + tid];
    }
    const float* Kb = Kq + (size_t)b*MN_ + pix0;
    #pragma unroll
    for (int r = 0; r < 4; ++r) {
      const int idx = r*256 + tid;
      kl[idx] = Kb[(size_t)(idx>>7)*N_ + (idx&127)];
    }
  }
  if (tid < 64) {
    const float inv = fbn[tid] / sqrtf(fbn[192+tid] + 1e-5f);
    invb[0][tid] = inv;
    invb[1][tid] = fbn[64+tid] - fbn[128+tid]*inv;
    invb[2][tid] = vb[tid];
  }
  const int lane = tid & 63, wv = tid >> 6;
  const int l15 = lane & 15, u = lane >> 4;

  short8 awv[4][2], awf[4][2];
  #pragma unroll
  for (int t = 0; t < 4; ++t) {
    #pragma unroll
    for (int kk = 0; kk < 2; ++kk) {
      const int roff = (t*16 + l15)*64 + kk*32 + u*8;
      awv[t][kk] = pack8(*(const float4*)(vw + roff), *(const float4*)(vw + roff + 4));
      awf[t][kk] = pack8(*(const float4*)(fw + roff), *(const float4*)(fw + roff + 4));
    }
  }
  __syncthreads();

  f32x4 av[4][2], af[4][2];
  #pragma unroll
  for (int t = 0; t < 4; ++t)
    #pragma unroll
    for (int s = 0; s < 2; ++s) { av[t][s] = (f32x4){0.f,0.f,0.f,0.f}; af[t][s] = (f32x4){0.f,0.f,0.f,0.f}; }

  const int pxw = wv*32;
  #pragma unroll
  for (int kk = 0; kk < 2; ++kk) {
    #pragma unroll
    for (int s = 0; s < 2; ++s) {
      const int pxl = pxw + s*16 + l15;
      const int off = pxl*64 + (((kk*4+u) ^ (pxl&7))<<3);
      const short8 bx = *(const short8*)(xl + off);
      const short8 bs = *(const short8*)(sl + off);
      #pragma unroll
      for (int t = 0; t < 4; ++t) {
        av[t][s] = __builtin_amdgcn_mfma_f32_16x16x32_bf16(awv[t][kk], bx, av[t][s], 0, 0, 0);
        af[t][s] = __builtin_amdgcn_mfma_f32_16x16x32_bf16(awf[t][kk], bs, af[t][s], 0, 0, 0);
      }
    }
  }

  // V = av + vb + relu6(bn(af)) in place
  #pragma unroll
  for (int t = 0; t < 4; ++t) {
    #pragma unroll
    for (int s = 0; s < 2; ++s) {
      #pragma unroll
      for (int r = 0; r < 4; ++r) {
        const int oc = t*16 + u*4 + r;
        av[t][s][r] = av[t][s][r] + invb[2][oc]
                    + relu6f(fmaf(af[t][s][r], invb[0][oc], invb[1][oc]));
      }
    }
  }

  // KV partial: per m, dot over lane's 2 px then butterfly over l&15
  const int jrev = 8*(l15&1) + 4*((l15>>1)&1) + 2*((l15>>2)&1) + ((l15>>3)&1);
  const int cdst = (jrev>>2)*16 + u*4 + (jrev&3);
  #pragma unroll
  for (int m = 0; m < 8; ++m) {
    const float k0 = kl[m*128 + pxw + l15];
    const float k1 = kl[m*128 + pxw + 16 + l15];
    float p[16];
    #pragma unroll
    for (int t = 0; t < 4; ++t)
      #pragma unroll
      for (int r = 0; r < 4; ++r)
        p[t*4+r] = fmaf(k0, av[t][0][r], k1 * av[t][1][r]);
    int nv = 16;
    #pragma unroll
    for (int mask = 1; mask <= 8; mask <<= 1) {
      nv >>= 1;
      const bool hi = (l15 & mask) != 0;
      #pragma unroll
      for (int i = 0; i < 8; ++i) {
        if (i < nv) {
          const float mine = hi ? p[i] : p[i+nv];
          const float th = __shfl_xor(mine, mask);
          p[i] = (hi ? p[i+nv] : p[i]) + th;
        }
      }
    }
    kvw[wv][m*64 + cdst] = p[0];
  }
  __syncthreads();
  float* kp = kv_part + (size_t)(b*NPG_ + pg)*512;
  kp[tid]       = (kvw[0][tid]+kvw[1][tid]) + (kvw[2][tid]+kvw[3][tid]);
  kp[tid+256]   = (kvw[0][tid+256]+kvw[1][tid+256]) + (kvw[2][tid+256]+kvw[3][tid+256]);
}

// ---------------------------------------------------------------------------
// K4: reduce per-block partials -> KV[b,512], Ksum[b,8].
// ---------------------------------------------------------------------------
__global__ __launch_bounds__(256) void k_red(const float* __restrict__ kv_part,
                                             const float* __restrict__ ks_part,
                                             float* __restrict__ KV,
                                             float* __restrict__ Ksum)
{
  __shared__ float red[4][64];
  __shared__ float rks[256];
  const int blk = blockIdx.x;          // 32 blocks: b = blk>>3, seg = blk&7
  const int b = blk >> 3, seg = blk & 7;
  const int t = threadIdx.x;
  const int i = seg*64 + (t & 63);
  const int sl = t >> 6;               // 0..3
  const float* base = kv_part + (size_t)b*NPG_*512 + i;
  float a = 0.0f;
  for (int g = sl; g < NPG_; g += 4) a += base[(size_t)g*512];
  red[sl][t & 63] = a;
  __syncthreads();
  if (t < 64)
    KV[b*512 + seg*64 + t] = (red[0][t] + red[1][t]) + (red[2][t] + red[3][t]);

  if (seg == 0) {
    const int m = t & 7, g0 = t >> 3;  // 32 slices per m
    float s2 = 0.0f;
    for (int g = g0; g < NPG2_; g += 32)
      s2 += ks_part[(size_t)b*NPG2_*8 + g*8 + m];
    rks[t] = s2;
    __syncthreads();
    if (t < 8) {
      float s3 = 0.0f;
      #pragma unroll
      for (int j2 = 0; j2 < 32; ++j2) s3 += rks[j2*8 + t];
      Ksum[b*8 + t] = s3;
    }
  }
}

// ---------------------------------------------------------------------------
// K5: Q on the fly; out = x + gamma * (Q^T KV) / (Q^T (Ksum+eps))
// ---------------------------------------------------------------------------
__global__ __launch_bounds__(256) void k_out(const float* __restrict__ x,
                                             const float* __restrict__ qw,
                                             const float* __restrict__ qb,
                                             const float* __restrict__ gamma,
                                             const float* __restrict__ KV,
                                             const float* __restrict__ Ksum,
                                             float* __restrict__ out)
{
  __shared__ __align__(16) float kvt[64*8];    // kvt[c][m]
  __shared__ __align__(16) float wqt[64*8];    // wqt[c][m]
  __shared__ float ksl[8];
  const int tid = threadIdx.x;
  const int b  = blockIdx.x / NPG2_;
  const int pg = blockIdx.x % NPG2_;
  const int pix0 = pg*256;
  const float* xb = x + (size_t)b*CN_ + pix0 + tid;

  for (int idx = tid; idx < 512; idx += 256) {
    const int m = idx >> 6, c = idx & 63;
    kvt[c*8 + m] = KV[b*512 + idx];
    wqt[c*8 + m] = qw[idx];
  }
  if (tid < 8) ksl[tid] = Ksum[b*8 + tid] + 1e-6f;
  __syncthreads();

  float q[8] = {0,0,0,0,0,0,0,0};
  #pragma unroll 8
  for (int c = 0; c < 64; ++c) {
    const float xv = xb[(size_t)c*N_];
    const float4 w0 = *(const float4*)&wqt[c*8];
    const float4 w1 = *(const float4*)&wqt[c*8+4];
    q[0] = fmaf(w0.x, xv, q[0]);
    q[1] = fmaf(w0.y, xv, q[1]);
    q[2] = fmaf(w0.z, xv, q[2]);
    q[3] = fmaf(w0.w, xv, q[3]);
    q[4] = fmaf(w1.x, xv, q[4]);
    q[5] = fmaf(w1.y, xv, q[5]);
    q[6] = fmaf(w1.z, xv, q[6]);
    q[7] = fmaf(w1.w, xv, q[7]);
  }
  float den = 0.0f;
  #pragma unroll
  for (int m = 0; m < 8; ++m) {
    q[m] = softplusf(q[m] + qb[m]);
    den  = fmaf(q[m], ksl[m], den);
  }
  const float sc = gamma[0] / den;

  float* ob = out + (size_t)b*CN_ + pix0 + tid;
  #pragma unroll 8
  for (int c = 0; c < 64; ++c) {
    const float4 k0 = *(const float4*)&kvt[c*8];
    const float4 k1 = *(const float4*)&kvt[c*8+4];
    float wv;
    wv = q[0]*k0.x;
    wv = fmaf(q[1], k0.y, wv);
    wv = fmaf(q[2], k0.z, wv);
    wv = fmaf(q[3], k0.w, wv);
    wv = fmaf(q[4], k1.x, wv);
    wv = fmaf(q[5], k1.y, wv);
    wv = fmaf(q[6], k1.z, wv);
    wv = fmaf(q[7], k1.w, wv);
    ob[(size_t)c*N_] = fmaf(sc, wv, xb[(size_t)c*N_]);
  }
}

// ---------------------------------------------------------------------------
extern "C" void kernel_launch(void* const* d_in, const int* in_sizes, int n_in,
                              void* d_out, int out_size, void* d_ws, size_t ws_size,
                              hipStream_t stream) {
  const float* x      = (const float*)d_in[0];
  const float* gamma  = (const float*)d_in[1];
  const float* q_w    = (const float*)d_in[2];
  const float* q_b    = (const float*)d_in[3];
  const float* k_w    = (const float*)d_in[4];
  const float* k_b    = (const float*)d_in[5];
  const float* v_w    = (const float*)d_in[6];
  const float* v_b    = (const float*)d_in[7];
  const float* fc1_w  = (const float*)d_in[8];
  const float* fc1_bn = (const float*)d_in[9];
  const float* c1_w   = (const float*)d_in[10];
  const float* c1_bn  = (const float*)d_in[11];
  const float* c2_w   = (const float*)d_in[12];
  const float* c2_bn  = (const float*)d_in[13];
  const float* fc2_w  = (const float*)d_in[14];
  const float* fc2_bn = (const float*)d_in[15];
  float* outp = (float*)d_out;

  float* ws = (float*)d_ws;
  float* h            = ws;                                  // fp32 NCHW; dead after k_dw
  unsigned short* xt  = (unsigned short*)(ws + (size_t)BCN_);      // bf16 swz-NHWC
  unsigned short* st  = xt + (size_t)BCN_;                         // bf16 swz-NHWC
  float* Kq           = ws + (size_t)2*BCN_;                       // fp32 [b][m][px]
  float* ks_part      = ws + (size_t)2*BCN_ + BMN_;                // 784*8
  float* kv           = ks_part + (size_t)B_*NPG2_*8;              // 2048
  float* ksum         = kv + 2048;                                 // 32
  float* kv_part      = h;                                         // alias (h dead)

  k_cast<<<dim3(B_*784), dim3(256), 0, stream>>>(x, xt);
  k_fc1m<<<dim3(B_*NPG2_), dim3(256), 0, stream>>>(xt, fc1_w, fc1_bn, k_w, k_b, h, Kq, ks_part);
  k_dw  <<<dim3(B_*C_*49), dim3(256), 0, stream>>>(h, c1_w, c2_w, c1_bn, c2_bn, st);
  k_vkm <<<dim3(B_*NPG_), dim3(256), 0, stream>>>(xt, st, v_w, v_b, fc2_w, fc2_bn, Kq, kv_part);
  k_red <<<dim3(32), dim3(256), 0, stream>>>(kv_part, ks_part, kv, ksum);
  k_out <<<dim3(B_*NPG2_), dim3(256), 0, stream>>>(x, q_w, q_b, gamma, kv, ksum, outp);
}

// Round 4
// 347.551 us; speedup vs baseline: 1.6318x; 1.6318x over previous
//
#include <hip/hip_runtime.h>
#include <math.h>

#define B_ 4
#define C_ 64
#define M_ 8
#define H_ 224
#define W_ 224
#define N_ (H_*W_)        // 50176
#define CN_ (C_*N_)       // 3211264
#define MN_ (M_*N_)       // 401408
#define BCN_ (B_*CN_)
#define BMN_ (B_*MN_)

__device__ __forceinline__ float relu6f(float v){ return fminf(fmaxf(v,0.0f),6.0f); }
__device__ __forceinline__ float softplusf(float v){
  return v > 0.0f ? v + log1pf(expf(-v)) : log1pf(expf(v));
}

#define FMA4(A, W, X) { A.x = fmaf((W), (X).x, A.x); A.y = fmaf((W), (X).y, A.y); \
                        A.z = fmaf((W), (X).z, A.z); A.w = fmaf((W), (X).w, A.w); }

// ---------------------------------------------------------------------------
// K1: h = relu6(bn(conv1x1(x))) AND K = softplus(conv1x1(x)+kb)
// 128-px tile, 64 oc/block. c in 8-wide slabs double-buffered in LDS.
// (round-0 verified version, byte-identical)
// ---------------------------------------------------------------------------
__global__ __launch_bounds__(256) void k_fc1k(const float* __restrict__ x,
                                              const float* __restrict__ w,
                                              const float* __restrict__ bn,
                                              const float* __restrict__ kw,
                                              const float* __restrict__ kb,
                                              float* __restrict__ h,
                                              float* __restrict__ Kq)
{
  __shared__ float xsl[2*1024];   // [buf][c'(8)][px(128)]
  __shared__ float wl [2*512];    // [buf][c'(8)][oc(64)]
  __shared__ float kt [512];      // [c(64)][m(8)]
  const int tid  = threadIdx.x;
  const int b    = blockIdx.x / 392;
  const int pg   = blockIdx.x % 392;
  const int pix0 = pg*128;
  const float* xb = x + (size_t)b*CN_ + pix0;

  for (int idx = tid; idx < 512; idx += 256) {
    const int c = idx >> 3, m = idx & 7;
    kt[idx] = kw[m*64 + c];
  }

  // staging roles
  const int scp = tid >> 5;            // c' 0..7
  const int spx = (tid & 31) << 2;     // px 0,4,..,124
  const int e0 = tid*2, e1 = tid*2+1;
  const int wc0 = e0 >> 6, wo0 = e0 & 63;
  const int wc1 = e1 >> 6, wo1 = e1 & 63;

  { // stage slab 0
    const float4 xr = *(const float4*)(xb + (size_t)scp*N_ + spx);
    const float w0r = w[wo0*64 + wc0];
    const float w1r = w[wo1*64 + wc1];
    *(float4*)&xsl[scp*128 + spx] = xr;
    wl[e0] = w0r; wl[e1] = w1r;
  }
  __syncthreads();

  const int lane = tid & 63, wv_ = tid >> 6;
  const int och  = 2*wv_ + (lane >> 5);   // 0..7
  const int ocb  = och*8;
  const int px4  = (lane & 31) << 2;

  float4 ah[8];
  float4 ak = {0,0,0,0};
  #pragma unroll
  for (int i = 0; i < 8; ++i) ah[i] = make_float4(0.f,0.f,0.f,0.f);

  for (int ck = 0; ck < 8; ++ck) {
    const int cur = ck & 1, nxt = cur ^ 1;
    const float* xc = &xsl[cur*1024];
    const float* wc = &wl[cur*512];
    float4 xr; float w0r, w1r;
    if (ck < 7) {                       // issue next slab's global loads now
      const int c0n = (ck+1)*8;
      xr  = *(const float4*)(xb + (size_t)(c0n + scp)*N_ + spx);
      w0r = w[wo0*64 + c0n + wc0];
      w1r = w[wo1*64 + c0n + wc1];
    }
    #pragma unroll
    for (int cp = 0; cp < 8; ++cp) {
      const float4 xv = *(const float4*)&xc[cp*128 + px4];
      const float4 w0 = *(const float4*)&wc[cp*64 + ocb];
      const float4 w1 = *(const float4*)&wc[cp*64 + ocb + 4];
      const float kvw = kt[(ck*8+cp)*8 + och];
      FMA4(ah[0], w0.x, xv); FMA4(ah[1], w0.y, xv);
      FMA4(ah[2], w0.z, xv); FMA4(ah[3], w0.w, xv);
      FMA4(ah[4], w1.x, xv); FMA4(ah[5], w1.y, xv);
      FMA4(ah[6], w1.z, xv); FMA4(ah[7], w1.w, xv);
      FMA4(ak, kvw, xv);
    }
    if (ck < 7) {                       // park staged regs into next buffer
      *(float4*)&xsl[nxt*1024 + scp*128 + spx] = xr;
      wl[nxt*512 + e0] = w0r; wl[nxt*512 + e1] = w1r;
    }
    __syncthreads();
  }

  float* hb = h + (size_t)b*CN_ + pix0 + px4;
  #pragma unroll
  for (int o = 0; o < 8; ++o) {
    const int oc = ocb + o;
    const float inv  = bn[oc] / sqrtf(bn[192+oc] + 1e-5f);
    const float beta = bn[64+oc] - bn[128+oc]*inv;
    float4 o4;
    o4.x = relu6f(fmaf(ah[o].x, inv, beta));
    o4.y = relu6f(fmaf(ah[o].y, inv, beta));
    o4.z = relu6f(fmaf(ah[o].z, inv, beta));
    o4.w = relu6f(fmaf(ah[o].w, inv, beta));
    *(float4*)(hb + (size_t)oc*N_) = o4;
  }
  { // K row m = och
    const float kbm = kb[och];
    float4 q;
    q.x = softplusf(ak.x + kbm); q.y = softplusf(ak.y + kbm);
    q.z = softplusf(ak.z + kbm); q.w = softplusf(ak.w + kbm);
    *(float4*)(Kq + (size_t)b*MN_ + (size_t)och*N_ + pix0 + px4) = q;
  }
}

// ---------------------------------------------------------------------------
// K2: s = relu6(bn1(dw5x5(h))) + relu6(bn2(dw3x3(h)))   32x32 tile per (b,c)
// (round-0 verified version, byte-identical)
// ---------------------------------------------------------------------------
__global__ __launch_bounds__(256) void k_dw(const float* __restrict__ h,
                                            const float* __restrict__ w5,
                                            const float* __restrict__ w3,
                                            const float* __restrict__ bn1,
                                            const float* __restrict__ bn2,
                                            float* __restrict__ s)
{
  __shared__ float tile[36*37];
  const int tid = threadIdx.x;
  const int blk = blockIdx.x;              // B*C*49
  const int t   = blk % 49;
  const int bc  = blk / 49;
  const int c   = bc & 63;
  const int tx0 = (t % 7) * 32;
  const int ty0 = (t / 7) * 32;
  const float* hb = h + (size_t)bc * N_;

  for (int idx = tid; idx < 1296; idx += 256) {
    const int ly = idx / 36, lx = idx - ly*36;
    const int gy = ty0 + ly - 2, gx = tx0 + lx - 2;
    float v = 0.0f;
    if (gy >= 0 && gy < H_ && gx >= 0 && gx < W_) v = hb[gy*W_ + gx];
    tile[ly*37 + lx] = v;
  }
  __syncthreads();

  float w5r[25], w3r[9];
  #pragma unroll
  for (int i = 0; i < 25; ++i) w5r[i] = w5[c*25 + i];
  #pragma unroll
  for (int i = 0; i < 9; ++i)  w3r[i] = w3[c*9 + i];
  const float inv1 = bn1[c] / sqrtf(bn1[192+c] + 1e-5f);
  const float bet1 = bn1[64+c] - bn1[128+c]*inv1;
  const float inv2 = bn2[c] / sqrtf(bn2[192+c] + 1e-5f);
  const float bet2 = bn2[64+c] - bn2[128+c]*inv2;

  const int ty  = tid >> 3;
  const int tx4 = (tid & 7) << 2;
  float a5[4] = {0,0,0,0}, a3[4] = {0,0,0,0};
  #pragma unroll
  for (int dy = 0; dy < 5; ++dy) {
    float r[8];
    #pragma unroll
    for (int i = 0; i < 8; ++i) r[i] = tile[(ty+dy)*37 + tx4 + i];
    #pragma unroll
    for (int dx = 0; dx < 5; ++dx) {
      const float wv = w5r[dy*5+dx];
      #pragma unroll
      for (int p = 0; p < 4; ++p) a5[p] = fmaf(wv, r[p+dx], a5[p]);
    }
    if (dy >= 1 && dy <= 3) {
      #pragma unroll
      for (int dx = 1; dx <= 3; ++dx) {
        const float wv = w3r[(dy-1)*3+(dx-1)];
        #pragma unroll
        for (int p = 0; p < 4; ++p) a3[p] = fmaf(wv, r[p+dx], a3[p]);
      }
    }
  }
  float* sb = s + (size_t)bc * N_ + (ty0+ty)*W_ + tx0 + tx4;
  float4 o4;
  o4.x = relu6f(fmaf(a5[0],inv1,bet1)) + relu6f(fmaf(a3[0],inv2,bet2));
  o4.y = relu6f(fmaf(a5[1],inv1,bet1)) + relu6f(fmaf(a3[1],inv2,bet2));
  o4.z = relu6f(fmaf(a5[2],inv1,bet1)) + relu6f(fmaf(a3[2],inv2,bet2));
  o4.w = relu6f(fmaf(a5[3],inv1,bet1)) + relu6f(fmaf(a3[3],inv2,bet2));
  *(float4*)sb = o4;
}

// ---------------------------------------------------------------------------
// K3: V = conv1x1(x,v_w)+v_b + relu6(bn(conv1x1(s,fc2_w)))
// (round-0 verified version, byte-identical)
// ---------------------------------------------------------------------------
__global__ __launch_bounds__(256) void k_v(const float* __restrict__ x,
                                           const float* __restrict__ s,
                                           const float* __restrict__ vw,
                                           const float* __restrict__ vb,
                                           const float* __restrict__ fw,
                                           const float* __restrict__ fbn,
                                           float* __restrict__ V)
{
  __shared__ float xsl[2*1024];
  __shared__ float ssl[2*1024];
  __shared__ float wvl[2*512];
  __shared__ float wfl[2*512];
  const int tid  = threadIdx.x;
  const int b    = blockIdx.x / 392;
  const int pg   = blockIdx.x % 392;
  const int pix0 = pg*128;
  const float* xb = x + (size_t)b*CN_ + pix0;
  const float* sb = s + (size_t)b*CN_ + pix0;

  const int scp = tid >> 5;
  const int spx = (tid & 31) << 2;
  const int e0 = tid*2, e1 = tid*2+1;
  const int wc0 = e0 >> 6, wo0 = e0 & 63;
  const int wc1 = e1 >> 6, wo1 = e1 & 63;

  { // stage slab 0
    const float4 xr = *(const float4*)(xb + (size_t)scp*N_ + spx);
    const float4 sr = *(const float4*)(sb + (size_t)scp*N_ + spx);
    const float a0 = vw[wo0*64 + wc0], a1 = vw[wo1*64 + wc1];
    const float f0 = fw[wo0*64 + wc0], f1 = fw[wo1*64 + wc1];
    *(float4*)&xsl[scp*128 + spx] = xr;
    *(float4*)&ssl[scp*128 + spx] = sr;
    wvl[e0] = a0; wvl[e1] = a1;
    wfl[e0] = f0; wfl[e1] = f1;
  }
  __syncthreads();

  const int lane = tid & 63, wv_ = tid >> 6;
  const int och  = 2*wv_ + (lane >> 5);
  const int ocb  = och*8;
  const int px4  = (lane & 31) << 2;

  float4 av[8], af[8];
  #pragma unroll
  for (int i = 0; i < 8; ++i) { av[i] = make_float4(0,0,0,0); af[i] = make_float4(0,0,0,0); }

  for (int ck = 0; ck < 8; ++ck) {
    const int cur = ck & 1, nxt = cur ^ 1;
    const float* xc = &xsl[cur*1024];
    const float* sc2 = &ssl[cur*1024];
    const float* wvc = &wvl[cur*512];
    const float* wfc = &wfl[cur*512];
    float4 xr, sr; float a0r, a1r, f0r, f1r;
    if (ck < 7) {
      const int c0n = (ck+1)*8;
      xr  = *(const float4*)(xb + (size_t)(c0n + scp)*N_ + spx);
      sr  = *(const float4*)(sb + (size_t)(c0n + scp)*N_ + spx);
      a0r = vw[wo0*64 + c0n + wc0]; a1r = vw[wo1*64 + c0n + wc1];
      f0r = fw[wo0*64 + c0n + wc0]; f1r = fw[wo1*64 + c0n + wc1];
    }
    #pragma unroll
    for (int cp = 0; cp < 8; ++cp) {
      const float4 xv = *(const float4*)&xc[cp*128 + px4];
      const float4 sv = *(const float4*)&sc2[cp*128 + px4];
      const float4 wa0 = *(const float4*)&wvc[cp*64 + ocb];
      const float4 wa1 = *(const float4*)&wvc[cp*64 + ocb + 4];
      const float4 wf0 = *(const float4*)&wfc[cp*64 + ocb];
      const float4 wf1 = *(const float4*)&wfc[cp*64 + ocb + 4];
      FMA4(av[0], wa0.x, xv); FMA4(av[1], wa0.y, xv);
      FMA4(av[2], wa0.z, xv); FMA4(av[3], wa0.w, xv);
      FMA4(av[4], wa1.x, xv); FMA4(av[5], wa1.y, xv);
      FMA4(av[6], wa1.z, xv); FMA4(av[7], wa1.w, xv);
      FMA4(af[0], wf0.x, sv); FMA4(af[1], wf0.y, sv);
      FMA4(af[2], wf0.z, sv); FMA4(af[3], wf0.w, sv);
      FMA4(af[4], wf1.x, sv); FMA4(af[5], wf1.y, sv);
      FMA4(af[6], wf1.z, sv); FMA4(af[7], wf1.w, sv);
    }
    if (ck < 7) {
      *(float4*)&xsl[nxt*1024 + scp*128 + spx] = xr;
      *(float4*)&ssl[nxt*1024 + scp*128 + spx] = sr;
      wvl[nxt*512 + e0] = a0r; wvl[nxt*512 + e1] = a1r;
      wfl[nxt*512 + e0] = f0r; wfl[nxt*512 + e1] = f1r;
    }
    __syncthreads();
  }

  float* Vb = V + (size_t)b*CN_ + pix0 + px4;
  #pragma unroll
  for (int o = 0; o < 8; ++o) {
    const int oc = ocb + o;
    const float inv  = fbn[oc] / sqrtf(fbn[192+oc] + 1e-5f);
    const float beta = fbn[64+oc] - fbn[128+oc]*inv;
    const float bias = vb[oc];
    float4 o4;
    o4.x = av[o].x + bias + relu6f(fmaf(af[o].x, inv, beta));
    o4.y = av[o].y + bias + relu6f(fmaf(af[o].y, inv, beta));
    o4.z = av[o].z + bias + relu6f(fmaf(af[o].z, inv, beta));
    o4.w = av[o].w + bias + relu6f(fmaf(af[o].w, inv, beta));
    *(float4*)(Vb + (size_t)oc*N_) = o4;
  }
}

// ---------------------------------------------------------------------------
// K4: KV[b,m,c] = sum_n K[b,m,n]*V[b,c,n];  Ksum[b,m] = sum_n K[b,m,n]
// NEW vs round-0: (a) n-loop vectorized to float4 (VMEM issues /4);
// (b) value-halving butterfly (63 shuffles vs 384) — this construction was
// correctness-verified in rounds 1-2. Atomics stay (mild 16-way contention).
// ---------------------------------------------------------------------------
__global__ __launch_bounds__(256) void k_kv(const float* __restrict__ V,
                                            const float* __restrict__ Kq,
                                            float* __restrict__ KV,
                                            float* __restrict__ Ksum)
{
  const int blk = blockIdx.x;
  const int b   = blk >> 7;
  const int rem = blk & 127;
  const int cg  = rem >> 4;
  const int ch  = rem & 15;
  const int tid = threadIdx.x;
  const int base = ch * 3136;
  const int end  = base + 3136;
  const float* Kb = Kq + (size_t)b*MN_;
  const float* Vb = V  + (size_t)b*CN_ + (size_t)(cg*8)*N_;

  float acc[64];
  #pragma unroll
  for (int i = 0; i < 64; ++i) acc[i] = 0.0f;
  float ks[8] = {0,0,0,0,0,0,0,0};

  for (int n4 = base + tid*4; n4 < end; n4 += 1024) {
    float4 kr[8];
    #pragma unroll
    for (int m2 = 0; m2 < 8; ++m2) kr[m2] = *(const float4*)(Kb + (size_t)m2*N_ + n4);
    #pragma unroll
    for (int m2 = 0; m2 < 8; ++m2)
      ks[m2] += (kr[m2].x + kr[m2].y) + (kr[m2].z + kr[m2].w);
    #pragma unroll
    for (int c8 = 0; c8 < 8; ++c8) {
      const float4 vv = *(const float4*)(Vb + (size_t)c8*N_ + n4);
      #pragma unroll
      for (int m2 = 0; m2 < 8; ++m2) {
        float t = acc[m2*8+c8];
        t = fmaf(kr[m2].x, vv.x, t);
        t = fmaf(kr[m2].y, vv.y, t);
        t = fmaf(kr[m2].z, vv.z, t);
        t = fmaf(kr[m2].w, vv.w, t);
        acc[m2*8+c8] = t;
      }
    }
  }
  const int lane = tid & 63;

  // value-halving butterfly: 64 values over 64 lanes -> 1 value/lane
  {
    int nv = 64;
    #pragma unroll
    for (int mask = 1; mask <= 32; mask <<= 1) {
      nv >>= 1;
      const bool hi = (lane & mask) != 0;
      #pragma unroll
      for (int i = 0; i < 32; ++i) {
        if (i < nv) {
          const float mine = hi ? acc[i] : acc[i+nv];
          const float th = __shfl_xor(mine, mask);
          acc[i] = (hi ? acc[i+nv] : acc[i]) + th;
        }
      }
    }
  }
  // lane holds value j = bitrev6(lane); j = m2*8 + c8
  const int j = 32*(lane & 1) + 16*((lane >> 1) & 1) + 8*((lane >> 2) & 1)
              + 4*((lane >> 3) & 1) + 2*((lane >> 4) & 1) + ((lane >> 5) & 1);
  atomicAdd(&KV[b*512 + (j >> 3)*64 + cg*8 + (j & 7)], acc[0]);

  if (cg == 0) {
    float mk = 0.0f;
    #pragma unroll
    for (int jj = 0; jj < 8; ++jj) {
      float v = ks[jj];
      v += __shfl_xor(v, 1);
      v += __shfl_xor(v, 2);
      v += __shfl_xor(v, 4);
      v += __shfl_xor(v, 8);
      v += __shfl_xor(v, 16);
      v += __shfl_xor(v, 32);
      if (lane == jj) mk = v;
    }
    if (lane < 8) atomicAdd(&Ksum[b*8 + lane], mk);
  }
}

// ---------------------------------------------------------------------------
// K5: Q on the fly; out = x + gamma * (Q^T KV) / (Q^T (Ksum+eps))
// NEW: x held in 64 REGISTERS per thread (fully-unrolled loops -> static
// indexing -> no scratch). No 64KB LDS stage (was capping 2 blocks/CU),
// no second HBM read of x. LDS = 4.2KB.
// ---------------------------------------------------------------------------
__global__ __launch_bounds__(256) void k_out(const float* __restrict__ x,
                                             const float* __restrict__ qw,
                                             const float* __restrict__ qb,
                                             const float* __restrict__ gamma,
                                             const float* __restrict__ KV,
                                             const float* __restrict__ Ksum,
                                             float* __restrict__ out)
{
  __shared__ __align__(16) float kvt[64*8];    // kvt[c][m]
  __shared__ __align__(16) float wqt[64*8];    // wqt[c][m]
  __shared__ float ksl[8];
  const int tid = threadIdx.x;
  const int b  = blockIdx.x / 196;
  const int pg = blockIdx.x % 196;
  const int pix0 = pg*256;
  const float* xb = x + (size_t)b*CN_ + pix0 + tid;

  for (int idx = tid; idx < 512; idx += 256) {
    const int m = idx >> 6, c = idx & 63;
    kvt[c*8 + m] = KV[b*512 + idx];
    wqt[c*8 + m] = qw[idx];
  }
  if (tid < 8) ksl[tid] = Ksum[b*8 + tid] + 1e-6f;
  __syncthreads();

  float xr[64];
  float q[8] = {0,0,0,0,0,0,0,0};
  #pragma unroll
  for (int c = 0; c < 64; ++c) {
    xr[c] = xb[(size_t)c*N_];
    const float4 w0 = *(const float4*)&wqt[c*8];
    const float4 w1 = *(const float4*)&wqt[c*8+4];
    q[0] = fmaf(w0.x, xr[c], q[0]);
    q[1] = fmaf(w0.y, xr[c], q[1]);
    q[2] = fmaf(w0.z, xr[c], q[2]);
    q[3] = fmaf(w0.w, xr[c], q[3]);
    q[4] = fmaf(w1.x, xr[c], q[4]);
    q[5] = fmaf(w1.y, xr[c], q[5]);
    q[6] = fmaf(w1.z, xr[c], q[6]);
    q[7] = fmaf(w1.w, xr[c], q[7]);
  }
  float den = 0.0f;
  #pragma unroll
  for (int m = 0; m < 8; ++m) {
    q[m] = softplusf(q[m] + qb[m]);
    den  = fmaf(q[m], ksl[m], den);
  }
  const float sc = gamma[0] / den;

  float* ob = out + (size_t)b*CN_ + pix0 + tid;
  #pragma unroll
  for (int c = 0; c < 64; ++c) {
    const float4 k0 = *(const float4*)&kvt[c*8];
    const float4 k1 = *(const float4*)&kvt[c*8+4];
    float wv;
    wv = q[0]*k0.x;
    wv = fmaf(q[1], k0.y, wv);
    wv = fmaf(q[2], k0.z, wv);
    wv = fmaf(q[3], k0.w, wv);
    wv = fmaf(q[4], k1.x, wv);
    wv = fmaf(q[5], k1.y, wv);
    wv = fmaf(q[6], k1.z, wv);
    wv = fmaf(q[7], k1.w, wv);
    ob[(size_t)c*N_] = fmaf(sc, wv, xr[c]);
  }
}

// ---------------------------------------------------------------------------
extern "C" void kernel_launch(void* const* d_in, const int* in_sizes, int n_in,
                              void* d_out, int out_size, void* d_ws, size_t ws_size,
                              hipStream_t stream) {
  const float* x      = (const float*)d_in[0];
  const float* gamma  = (const float*)d_in[1];
  const float* q_w    = (const float*)d_in[2];
  const float* q_b    = (const float*)d_in[3];
  const float* k_w    = (const float*)d_in[4];
  const float* k_b    = (const float*)d_in[5];
  const float* v_w    = (const float*)d_in[6];
  const float* v_b    = (const float*)d_in[7];
  const float* fc1_w  = (const float*)d_in[8];
  const float* fc1_bn = (const float*)d_in[9];
  const float* c1_w   = (const float*)d_in[10];
  const float* c1_bn  = (const float*)d_in[11];
  const float* c2_w   = (const float*)d_in[12];
  const float* c2_bn  = (const float*)d_in[13];
  const float* fc2_w  = (const float*)d_in[14];
  const float* fc2_bn = (const float*)d_in[15];
  float* outp = (float*)d_out;

  float* ws   = (float*)d_ws;
  float* bufA = ws;                        // h, later reused for V
  float* bufS = ws + (size_t)BCN_;
  float* bufK = ws + (size_t)2*BCN_;
  float* kv   = ws + (size_t)2*BCN_ + BMN_;
  float* ksum = kv + 2048;

  hipMemsetAsync(kv, 0, (2048 + 32)*sizeof(float), stream);

  k_fc1k<<<dim3(B_*392), dim3(256), 0, stream>>>(x, fc1_w, fc1_bn, k_w, k_b, bufA, bufK);
  k_dw  <<<dim3(B_*C_*49), dim3(256), 0, stream>>>(bufA, c1_w, c2_w, c1_bn, c2_bn, bufS);
  k_v   <<<dim3(B_*392), dim3(256), 0, stream>>>(x, bufS, v_w, v_b, fc2_w, fc2_bn, bufA);
  k_kv  <<<dim3(512), dim3(256), 0, stream>>>(bufA, bufK, kv, ksum);
  k_out <<<dim3(B_*196), dim3(256), 0, stream>>>(x, q_w, q_b, gamma, kv, ksum, outp);
}

// Round 5
// 300.941 us; speedup vs baseline: 1.8845x; 1.1549x over previous
//
#include <hip/hip_runtime.h>
#include <math.h>

#define B_ 4
#define C_ 64
#define M_ 8
#define H_ 224
#define W_ 224
#define N_ (H_*W_)        // 50176
#define CN_ (C_*N_)       // 3211264
#define MN_ (M_*N_)       // 401408
#define BCN_ (B_*CN_)
#define BMN_ (B_*MN_)

__device__ __forceinline__ float relu6f(float v){ return fminf(fmaxf(v,0.0f),6.0f); }
__device__ __forceinline__ float softplusf(float v){
  return v > 0.0f ? v + log1pf(expf(-v)) : log1pf(expf(v));
}

#define FMA4(A, W, X) { A.x = fmaf((W), (X).x, A.x); A.y = fmaf((W), (X).y, A.y); \
                        A.z = fmaf((W), (X).z, A.z); A.w = fmaf((W), (X).w, A.w); }

// ---------------------------------------------------------------------------
// K1: h = relu6(bn(conv1x1(x))) AND K = softplus(conv1x1(x)+kb)
// (round-0 verified version, byte-identical)
// ---------------------------------------------------------------------------
__global__ __launch_bounds__(256) void k_fc1k(const float* __restrict__ x,
                                              const float* __restrict__ w,
                                              const float* __restrict__ bn,
                                              const float* __restrict__ kw,
                                              const float* __restrict__ kb,
                                              float* __restrict__ h,
                                              float* __restrict__ Kq)
{
  __shared__ float xsl[2*1024];   // [buf][c'(8)][px(128)]
  __shared__ float wl [2*512];    // [buf][c'(8)][oc(64)]
  __shared__ float kt [512];      // [c(64)][m(8)]
  const int tid  = threadIdx.x;
  const int b    = blockIdx.x / 392;
  const int pg   = blockIdx.x % 392;
  const int pix0 = pg*128;
  const float* xb = x + (size_t)b*CN_ + pix0;

  for (int idx = tid; idx < 512; idx += 256) {
    const int c = idx >> 3, m = idx & 7;
    kt[idx] = kw[m*64 + c];
  }

  // staging roles
  const int scp = tid >> 5;            // c' 0..7
  const int spx = (tid & 31) << 2;     // px 0,4,..,124
  const int e0 = tid*2, e1 = tid*2+1;
  const int wc0 = e0 >> 6, wo0 = e0 & 63;
  const int wc1 = e1 >> 6, wo1 = e1 & 63;

  { // stage slab 0
    const float4 xr = *(const float4*)(xb + (size_t)scp*N_ + spx);
    const float w0r = w[wo0*64 + wc0];
    const float w1r = w[wo1*64 + wc1];
    *(float4*)&xsl[scp*128 + spx] = xr;
    wl[e0] = w0r; wl[e1] = w1r;
  }
  __syncthreads();

  const int lane = tid & 63, wv_ = tid >> 6;
  const int och  = 2*wv_ + (lane >> 5);   // 0..7
  const int ocb  = och*8;
  const int px4  = (lane & 31) << 2;

  float4 ah[8];
  float4 ak = {0,0,0,0};
  #pragma unroll
  for (int i = 0; i < 8; ++i) ah[i] = make_float4(0.f,0.f,0.f,0.f);

  for (int ck = 0; ck < 8; ++ck) {
    const int cur = ck & 1, nxt = cur ^ 1;
    const float* xc = &xsl[cur*1024];
    const float* wc = &wl[cur*512];
    float4 xr; float w0r, w1r;
    if (ck < 7) {                       // issue next slab's global loads now
      const int c0n = (ck+1)*8;
      xr  = *(const float4*)(xb + (size_t)(c0n + scp)*N_ + spx);
      w0r = w[wo0*64 + c0n + wc0];
      w1r = w[wo1*64 + c0n + wc1];
    }
    #pragma unroll
    for (int cp = 0; cp < 8; ++cp) {
      const float4 xv = *(const float4*)&xc[cp*128 + px4];
      const float4 w0 = *(const float4*)&wc[cp*64 + ocb];
      const float4 w1 = *(const float4*)&wc[cp*64 + ocb + 4];
      const float kvw = kt[(ck*8+cp)*8 + och];
      FMA4(ah[0], w0.x, xv); FMA4(ah[1], w0.y, xv);
      FMA4(ah[2], w0.z, xv); FMA4(ah[3], w0.w, xv);
      FMA4(ah[4], w1.x, xv); FMA4(ah[5], w1.y, xv);
      FMA4(ah[6], w1.z, xv); FMA4(ah[7], w1.w, xv);
      FMA4(ak, kvw, xv);
    }
    if (ck < 7) {                       // park staged regs into next buffer
      *(float4*)&xsl[nxt*1024 + scp*128 + spx] = xr;
      wl[nxt*512 + e0] = w0r; wl[nxt*512 + e1] = w1r;
    }
    __syncthreads();
  }

  float* hb = h + (size_t)b*CN_ + pix0 + px4;
  #pragma unroll
  for (int o = 0; o < 8; ++o) {
    const int oc = ocb + o;
    const float inv  = bn[oc] / sqrtf(bn[192+oc] + 1e-5f);
    const float beta = bn[64+oc] - bn[128+oc]*inv;
    float4 o4;
    o4.x = relu6f(fmaf(ah[o].x, inv, beta));
    o4.y = relu6f(fmaf(ah[o].y, inv, beta));
    o4.z = relu6f(fmaf(ah[o].z, inv, beta));
    o4.w = relu6f(fmaf(ah[o].w, inv, beta));
    *(float4*)(hb + (size_t)oc*N_) = o4;
  }
  { // K row m = och
    const float kbm = kb[och];
    float4 q;
    q.x = softplusf(ak.x + kbm); q.y = softplusf(ak.y + kbm);
    q.z = softplusf(ak.z + kbm); q.w = softplusf(ak.w + kbm);
    *(float4*)(Kq + (size_t)b*MN_ + (size_t)och*N_ + pix0 + px4) = q;
  }
}

// ---------------------------------------------------------------------------
// K2: s = relu6(bn1(dw5x5(h))) + relu6(bn2(dw3x3(h)))   32x32 tile per (b,c)
// (round-0 verified version, byte-identical)
// ---------------------------------------------------------------------------
__global__ __launch_bounds__(256) void k_dw(const float* __restrict__ h,
                                            const float* __restrict__ w5,
                                            const float* __restrict__ w3,
                                            const float* __restrict__ bn1,
                                            const float* __restrict__ bn2,
                                            float* __restrict__ s)
{
  __shared__ float tile[36*37];
  const int tid = threadIdx.x;
  const int blk = blockIdx.x;              // B*C*49
  const int t   = blk % 49;
  const int bc  = blk / 49;
  const int c   = bc & 63;
  const int tx0 = (t % 7) * 32;
  const int ty0 = (t / 7) * 32;
  const float* hb = h + (size_t)bc * N_;

  for (int idx = tid; idx < 1296; idx += 256) {
    const int ly = idx / 36, lx = idx - ly*36;
    const int gy = ty0 + ly - 2, gx = tx0 + lx - 2;
    float v = 0.0f;
    if (gy >= 0 && gy < H_ && gx >= 0 && gx < W_) v = hb[gy*W_ + gx];
    tile[ly*37 + lx] = v;
  }
  __syncthreads();

  float w5r[25], w3r[9];
  #pragma unroll
  for (int i = 0; i < 25; ++i) w5r[i] = w5[c*25 + i];
  #pragma unroll
  for (int i = 0; i < 9; ++i)  w3r[i] = w3[c*9 + i];
  const float inv1 = bn1[c] / sqrtf(bn1[192+c] + 1e-5f);
  const float bet1 = bn1[64+c] - bn1[128+c]*inv1;
  const float inv2 = bn2[c] / sqrtf(bn2[192+c] + 1e-5f);
  const float bet2 = bn2[64+c] - bn2[128+c]*inv2;

  const int ty  = tid >> 3;
  const int tx4 = (tid & 7) << 2;
  float a5[4] = {0,0,0,0}, a3[4] = {0,0,0,0};
  #pragma unroll
  for (int dy = 0; dy < 5; ++dy) {
    float r[8];
    #pragma unroll
    for (int i = 0; i < 8; ++i) r[i] = tile[(ty+dy)*37 + tx4 + i];
    #pragma unroll
    for (int dx = 0; dx < 5; ++dx) {
      const float wv = w5r[dy*5+dx];
      #pragma unroll
      for (int p = 0; p < 4; ++p) a5[p] = fmaf(wv, r[p+dx], a5[p]);
    }
    if (dy >= 1 && dy <= 3) {
      #pragma unroll
      for (int dx = 1; dx <= 3; ++dx) {
        const float wv = w3r[(dy-1)*3+(dx-1)];
        #pragma unroll
        for (int p = 0; p < 4; ++p) a3[p] = fmaf(wv, r[p+dx], a3[p]);
      }
    }
  }
  float* sb = s + (size_t)bc * N_ + (ty0+ty)*W_ + tx0 + tx4;
  float4 o4;
  o4.x = relu6f(fmaf(a5[0],inv1,bet1)) + relu6f(fmaf(a3[0],inv2,bet2));
  o4.y = relu6f(fmaf(a5[1],inv1,bet1)) + relu6f(fmaf(a3[1],inv2,bet2));
  o4.z = relu6f(fmaf(a5[2],inv1,bet1)) + relu6f(fmaf(a3[2],inv2,bet2));
  o4.w = relu6f(fmaf(a5[3],inv1,bet1)) + relu6f(fmaf(a3[3],inv2,bet2));
  *(float4*)sb = o4;
}

// ---------------------------------------------------------------------------
// K3: V = conv1x1(x,v_w)+v_b + relu6(bn(conv1x1(s,fc2_w)))
// NEW: also computes Q = softplus(conv1x1(x,q_w)+q_b) — exactly the k_fc1k
// K-fold pattern (qt table + 1 FMA4/iter). Q is written into bufS's c<8
// slots: this block is the ONLY reader of s at these pixels and all its
// s-reads completed before the epilogue -> race-free, zero extra workspace.
// This removes k_out's need to touch x twice (round-4 spill fix).
// ---------------------------------------------------------------------------
__global__ __launch_bounds__(256) void k_v(const float* __restrict__ x,
                                           float* __restrict__ s,      // in: s; out: Q in c<8 slots
                                           const float* __restrict__ vw,
                                           const float* __restrict__ vb,
                                           const float* __restrict__ fw,
                                           const float* __restrict__ fbn,
                                           const float* __restrict__ qw_,
                                           const float* __restrict__ qb_,
                                           float* __restrict__ V)
{
  __shared__ float xsl[2*1024];
  __shared__ float ssl[2*1024];
  __shared__ float wvl[2*512];
  __shared__ float wfl[2*512];
  __shared__ float qt [512];      // [c(64)][m(8)]
  const int tid  = threadIdx.x;
  const int b    = blockIdx.x / 392;
  const int pg   = blockIdx.x % 392;
  const int pix0 = pg*128;
  const float* xb = x + (size_t)b*CN_ + pix0;
  const float* sb = s + (size_t)b*CN_ + pix0;

  for (int idx = tid; idx < 512; idx += 256) {
    const int c = idx >> 3, m = idx & 7;
    qt[idx] = qw_[m*64 + c];
  }

  const int scp = tid >> 5;
  const int spx = (tid & 31) << 2;
  const int e0 = tid*2, e1 = tid*2+1;
  const int wc0 = e0 >> 6, wo0 = e0 & 63;
  const int wc1 = e1 >> 6, wo1 = e1 & 63;

  { // stage slab 0
    const float4 xr = *(const float4*)(xb + (size_t)scp*N_ + spx);
    const float4 sr = *(const float4*)(sb + (size_t)scp*N_ + spx);
    const float a0 = vw[wo0*64 + wc0], a1 = vw[wo1*64 + wc1];
    const float f0 = fw[wo0*64 + wc0], f1 = fw[wo1*64 + wc1];
    *(float4*)&xsl[scp*128 + spx] = xr;
    *(float4*)&ssl[scp*128 + spx] = sr;
    wvl[e0] = a0; wvl[e1] = a1;
    wfl[e0] = f0; wfl[e1] = f1;
  }
  __syncthreads();

  const int lane = tid & 63, wv_ = tid >> 6;
  const int och  = 2*wv_ + (lane >> 5);
  const int ocb  = och*8;
  const int px4  = (lane & 31) << 2;

  float4 av[8], af[8];
  float4 aq = {0,0,0,0};
  #pragma unroll
  for (int i = 0; i < 8; ++i) { av[i] = make_float4(0,0,0,0); af[i] = make_float4(0,0,0,0); }

  for (int ck = 0; ck < 8; ++ck) {
    const int cur = ck & 1, nxt = cur ^ 1;
    const float* xc = &xsl[cur*1024];
    const float* sc2 = &ssl[cur*1024];
    const float* wvc = &wvl[cur*512];
    const float* wfc = &wfl[cur*512];
    float4 xr, sr; float a0r, a1r, f0r, f1r;
    if (ck < 7) {
      const int c0n = (ck+1)*8;
      xr  = *(const float4*)(xb + (size_t)(c0n + scp)*N_ + spx);
      sr  = *(const float4*)(sb + (size_t)(c0n + scp)*N_ + spx);
      a0r = vw[wo0*64 + c0n + wc0]; a1r = vw[wo1*64 + c0n + wc1];
      f0r = fw[wo0*64 + c0n + wc0]; f1r = fw[wo1*64 + c0n + wc1];
    }
    #pragma unroll
    for (int cp = 0; cp < 8; ++cp) {
      const float4 xv = *(const float4*)&xc[cp*128 + px4];
      const float4 sv = *(const float4*)&sc2[cp*128 + px4];
      const float4 wa0 = *(const float4*)&wvc[cp*64 + ocb];
      const float4 wa1 = *(const float4*)&wvc[cp*64 + ocb + 4];
      const float4 wf0 = *(const float4*)&wfc[cp*64 + ocb];
      const float4 wf1 = *(const float4*)&wfc[cp*64 + ocb + 4];
      const float qvw = qt[(ck*8+cp)*8 + och];
      FMA4(av[0], wa0.x, xv); FMA4(av[1], wa0.y, xv);
      FMA4(av[2], wa0.z, xv); FMA4(av[3], wa0.w, xv);
      FMA4(av[4], wa1.x, xv); FMA4(av[5], wa1.y, xv);
      FMA4(av[6], wa1.z, xv); FMA4(av[7], wa1.w, xv);
      FMA4(af[0], wf0.x, sv); FMA4(af[1], wf0.y, sv);
      FMA4(af[2], wf0.z, sv); FMA4(af[3], wf0.w, sv);
      FMA4(af[4], wf1.x, sv); FMA4(af[5], wf1.y, sv);
      FMA4(af[6], wf1.z, sv); FMA4(af[7], wf1.w, sv);
      FMA4(aq, qvw, xv);
    }
    if (ck < 7) {
      *(float4*)&xsl[nxt*1024 + scp*128 + spx] = xr;
      *(float4*)&ssl[nxt*1024 + scp*128 + spx] = sr;
      wvl[nxt*512 + e0] = a0r; wvl[nxt*512 + e1] = a1r;
      wfl[nxt*512 + e0] = f0r; wfl[nxt*512 + e1] = f1r;
    }
    __syncthreads();
  }

  float* Vb = V + (size_t)b*CN_ + pix0 + px4;
  #pragma unroll
  for (int o = 0; o < 8; ++o) {
    const int oc = ocb + o;
    const float inv  = fbn[oc] / sqrtf(fbn[192+oc] + 1e-5f);
    const float beta = fbn[64+oc] - fbn[128+oc]*inv;
    const float bias = vb[oc];
    float4 o4;
    o4.x = av[o].x + bias + relu6f(fmaf(af[o].x, inv, beta));
    o4.y = av[o].y + bias + relu6f(fmaf(af[o].y, inv, beta));
    o4.z = av[o].z + bias + relu6f(fmaf(af[o].z, inv, beta));
    o4.w = av[o].w + bias + relu6f(fmaf(af[o].w, inv, beta));
    *(float4*)(Vb + (size_t)oc*N_) = o4;
  }
  { // Q row m = och -> into s's c=och slot at this block's pixels (race-free)
    const float qbm = qb_[och];
    float4 q;
    q.x = softplusf(aq.x + qbm); q.y = softplusf(aq.y + qbm);
    q.z = softplusf(aq.z + qbm); q.w = softplusf(aq.w + qbm);
    *(float4*)(s + (size_t)b*CN_ + (size_t)och*N_ + pix0 + px4) = q;
  }
}

// ---------------------------------------------------------------------------
// K4: KV[b,m,c] = sum_n K[b,m,n]*V[b,c,n];  Ksum[b,m] = sum_n K[b,m,n]
// (round-3 float4 + value-halving butterfly version, verified)
// ---------------------------------------------------------------------------
__global__ __launch_bounds__(256) void k_kv(const float* __restrict__ V,
                                            const float* __restrict__ Kq,
                                            float* __restrict__ KV,
                                            float* __restrict__ Ksum)
{
  const int blk = blockIdx.x;
  const int b   = blk >> 7;
  const int rem = blk & 127;
  const int cg  = rem >> 4;
  const int ch  = rem & 15;
  const int tid = threadIdx.x;
  const int base = ch * 3136;
  const int end  = base + 3136;
  const float* Kb = Kq + (size_t)b*MN_;
  const float* Vb = V  + (size_t)b*CN_ + (size_t)(cg*8)*N_;

  float acc[64];
  #pragma unroll
  for (int i = 0; i < 64; ++i) acc[i] = 0.0f;
  float ks[8] = {0,0,0,0,0,0,0,0};

  for (int n4 = base + tid*4; n4 < end; n4 += 1024) {
    float4 kr[8];
    #pragma unroll
    for (int m2 = 0; m2 < 8; ++m2) kr[m2] = *(const float4*)(Kb + (size_t)m2*N_ + n4);
    #pragma unroll
    for (int m2 = 0; m2 < 8; ++m2)
      ks[m2] += (kr[m2].x + kr[m2].y) + (kr[m2].z + kr[m2].w);
    #pragma unroll
    for (int c8 = 0; c8 < 8; ++c8) {
      const float4 vv = *(const float4*)(Vb + (size_t)c8*N_ + n4);
      #pragma unroll
      for (int m2 = 0; m2 < 8; ++m2) {
        float t = acc[m2*8+c8];
        t = fmaf(kr[m2].x, vv.x, t);
        t = fmaf(kr[m2].y, vv.y, t);
        t = fmaf(kr[m2].z, vv.z, t);
        t = fmaf(kr[m2].w, vv.w, t);
        acc[m2*8+c8] = t;
      }
    }
  }
  const int lane = tid & 63;

  // value-halving butterfly: 64 values over 64 lanes -> 1 value/lane
  {
    int nv = 64;
    #pragma unroll
    for (int mask = 1; mask <= 32; mask <<= 1) {
      nv >>= 1;
      const bool hi = (lane & mask) != 0;
      #pragma unroll
      for (int i = 0; i < 32; ++i) {
        if (i < nv) {
          const float mine = hi ? acc[i] : acc[i+nv];
          const float th = __shfl_xor(mine, mask);
          acc[i] = (hi ? acc[i+nv] : acc[i]) + th;
        }
      }
    }
  }
  // lane holds value j = bitrev6(lane); j = m2*8 + c8
  const int j = 32*(lane & 1) + 16*((lane >> 1) & 1) + 8*((lane >> 2) & 1)
              + 4*((lane >> 3) & 1) + 2*((lane >> 4) & 1) + ((lane >> 5) & 1);
  atomicAdd(&KV[b*512 + (j >> 3)*64 + cg*8 + (j & 7)], acc[0]);

  if (cg == 0) {
    float mk = 0.0f;
    #pragma unroll
    for (int jj = 0; jj < 8; ++jj) {
      float v = ks[jj];
      v += __shfl_xor(v, 1);
      v += __shfl_xor(v, 2);
      v += __shfl_xor(v, 4);
      v += __shfl_xor(v, 8);
      v += __shfl_xor(v, 16);
      v += __shfl_xor(v, 32);
      if (lane == jj) mk = v;
    }
    if (lane < 8) atomicAdd(&Ksum[b*8 + lane], mk);
  }
}

// ---------------------------------------------------------------------------
// K5: out = x + gamma * (Q^T KV) / (Q^T (Ksum+eps)); Q precomputed by k_v
// (read from Qbuf=bufS c<8 slots). Single pass over x, no xr[64], no big LDS.
// ---------------------------------------------------------------------------
__global__ __launch_bounds__(256) void k_out(const float* __restrict__ x,
                                             const float* __restrict__ Qbuf,
                                             const float* __restrict__ gamma,
                                             const float* __restrict__ KV,
                                             const float* __restrict__ Ksum,
                                             float* __restrict__ out)
{
  __shared__ __align__(16) float kvt[64*8];    // kvt[c][m]
  __shared__ float ksl[8];
  const int tid = threadIdx.x;
  const int b  = blockIdx.x / 196;
  const int pg = blockIdx.x % 196;
  const int pix0 = pg*256;
  const float* xb = x + (size_t)b*CN_ + pix0 + tid;
  const float* Qb = Qbuf + (size_t)b*CN_ + pix0 + tid;

  for (int idx = tid; idx < 512; idx += 256) {
    const int m = idx >> 6, c = idx & 63;
    kvt[c*8 + m] = KV[b*512 + idx];
  }
  if (tid < 8) ksl[tid] = Ksum[b*8 + tid] + 1e-6f;
  __syncthreads();

  float q[8];
  #pragma unroll
  for (int m = 0; m < 8; ++m) q[m] = Qb[(size_t)m*N_];   // already softplus'd
  float den = 0.0f;
  #pragma unroll
  for (int m = 0; m < 8; ++m) den = fmaf(q[m], ksl[m], den);
  const float sc = gamma[0] / den;

  float* ob = out + (size_t)b*CN_ + pix0 + tid;
  #pragma unroll 8
  for (int c = 0; c < 64; ++c) {
    const float4 k0 = *(const float4*)&kvt[c*8];
    const float4 k1 = *(const float4*)&kvt[c*8+4];
    float wv;
    wv = q[0]*k0.x;
    wv = fmaf(q[1], k0.y, wv);
    wv = fmaf(q[2], k0.z, wv);
    wv = fmaf(q[3], k0.w, wv);
    wv = fmaf(q[4], k1.x, wv);
    wv = fmaf(q[5], k1.y, wv);
    wv = fmaf(q[6], k1.z, wv);
    wv = fmaf(q[7], k1.w, wv);
    ob[(size_t)c*N_] = fmaf(sc, wv, xb[(size_t)c*N_]);
  }
}

// ---------------------------------------------------------------------------
extern "C" void kernel_launch(void* const* d_in, const int* in_sizes, int n_in,
                              void* d_out, int out_size, void* d_ws, size_t ws_size,
                              hipStream_t stream) {
  const float* x      = (const float*)d_in[0];
  const float* gamma  = (const float*)d_in[1];
  const float* q_w    = (const float*)d_in[2];
  const float* q_b    = (const float*)d_in[3];
  const float* k_w    = (const float*)d_in[4];
  const float* k_b    = (const float*)d_in[5];
  const float* v_w    = (const float*)d_in[6];
  const float* v_b    = (const float*)d_in[7];
  const float* fc1_w  = (const float*)d_in[8];
  const float* fc1_bn = (const float*)d_in[9];
  const float* c1_w   = (const float*)d_in[10];
  const float* c1_bn  = (const float*)d_in[11];
  const float* c2_w   = (const float*)d_in[12];
  const float* c2_bn  = (const float*)d_in[13];
  const float* fc2_w  = (const float*)d_in[14];
  const float* fc2_bn = (const float*)d_in[15];
  float* outp = (float*)d_out;

  float* ws   = (float*)d_ws;
  float* bufA = ws;                        // h, later reused for V
  float* bufS = ws + (size_t)BCN_;         // s; c<8 slots become Q after k_v
  float* bufK = ws + (size_t)2*BCN_;
  float* kv   = ws + (size_t)2*BCN_ + BMN_;
  float* ksum = kv + 2048;

  hipMemsetAsync(kv, 0, (2048 + 32)*sizeof(float), stream);

  k_fc1k<<<dim3(B_*392), dim3(256), 0, stream>>>(x, fc1_w, fc1_bn, k_w, k_b, bufA, bufK);
  k_dw  <<<dim3(B_*C_*49), dim3(256), 0, stream>>>(bufA, c1_w, c2_w, c1_bn, c2_bn, bufS);
  k_v   <<<dim3(B_*392), dim3(256), 0, stream>>>(x, bufS, v_w, v_b, fc2_w, fc2_bn, q_w, q_b, bufA);
  k_kv  <<<dim3(512), dim3(256), 0, stream>>>(bufA, bufK, kv, ksum);
  k_out <<<dim3(B_*196), dim3(256), 0, stream>>>(x, bufS, gamma, kv, ksum, outp);
}